// Round 2
// baseline (474.810 us; speedup 1.0000x reference)
//
#include <hip/hip_runtime.h>
#include <hip/hip_bf16.h>

// Problem constants
#define B_   4096
#define POOL 1024
#define SEL  5
#define PLEN 5
#define DIM  768
#define EPS  1e-8f
#define PF   (PLEN * DIM)      // 3840 floats per selected prompt
#define SPAN (4 * SEL * PF)    // 76800 floats: output span of one 4-row block

// Scratch layout (ALL inside the selection output region; d_ws is unused):
//   span b  = sel + b*SPAN   (rows 4b..4b+3 of the final gather output)
//   match row r lives at span(r>>2) + (r&3)*POOL   (first 4096 floats of span)
//   qn[4096] at sel + 4096 (span 0), kn[1024] at sel + 8192 (span 0)
// Hazard analysis: norms writes qn/kn -> gemm reads them + writes match
// (disjoint) -> fused topk+gather: each block reads ONLY its own span's
// match rows, barriers, then overwrites ONLY its own span. No cross-block
// read/write overlap; stream order covers the rest.

// ---------------------------------------------------------------------------
// Kernel 1: row norms. One wave per row.
__global__ __launch_bounds__(256) void norms_kernel(
    const float* __restrict__ query, const float* __restrict__ pkey,
    float* __restrict__ qn, float* __restrict__ kn) {
    int wave = (blockIdx.x * blockDim.x + threadIdx.x) >> 6;
    int lane = threadIdx.x & 63;
    if (wave >= B_ + POOL) return;
    const float* src;
    float* dst;
    if (wave < B_) { src = query + (size_t)wave * DIM; dst = qn + wave; }
    else           { src = pkey  + (size_t)(wave - B_) * DIM; dst = kn + (wave - B_); }
    float s = 0.f;
    #pragma unroll
    for (int t = 0; t < DIM / 64; ++t) {
        float x = src[lane + (t << 6)];
        s = fmaf(x, x, s);
    }
    #pragma unroll
    for (int m = 1; m <= 32; m <<= 1) s += __shfl_xor(s, m);
    if (lane == 0) *dst = sqrtf(s);
}

// ---------------------------------------------------------------------------
// Kernel 2: match[b][p] = 1 - dot(query[b], pkey[p]) / max(qn[b]*kn[p], EPS)
// 64x64 tile per block, K-chunks of 16, 256 threads, 4x4 acc per thread.
// match rows are written in the span-interleaved layout described above.
#define BQ 64
#define BP 64
#define KT 16
#define LDT 68

__global__ __launch_bounds__(256) void match_gemm(
    const float* __restrict__ query, const float* __restrict__ pkey,
    const float* __restrict__ qn, const float* __restrict__ kn,
    float* __restrict__ matchbase) {
    __shared__ float As[KT][LDT];
    __shared__ float Bs[KT][LDT];

    const int pbase = blockIdx.x * BP;
    const int qbase = blockIdx.y * BQ;
    const int tid = threadIdx.x;

    const int lrow = tid >> 2;
    const int ld4  = (tid & 3) << 2;

    const int myq = (tid & 15) << 2;
    const int myp = (tid >> 4) << 2;

    float acc[4][4];
    #pragma unroll
    for (int i = 0; i < 4; ++i)
        #pragma unroll
        for (int j = 0; j < 4; ++j) acc[i][j] = 0.f;

    for (int d0 = 0; d0 < DIM; d0 += KT) {
        float4 qv = *(const float4*)(query + (size_t)(qbase + lrow) * DIM + d0 + ld4);
        float4 kv = *(const float4*)(pkey  + (size_t)(pbase + lrow) * DIM + d0 + ld4);
        __syncthreads();   // previous iteration's LDS reads complete
        As[ld4 + 0][lrow] = qv.x; As[ld4 + 1][lrow] = qv.y;
        As[ld4 + 2][lrow] = qv.z; As[ld4 + 3][lrow] = qv.w;
        Bs[ld4 + 0][lrow] = kv.x; Bs[ld4 + 1][lrow] = kv.y;
        Bs[ld4 + 2][lrow] = kv.z; Bs[ld4 + 3][lrow] = kv.w;
        __syncthreads();
        #pragma unroll
        for (int d = 0; d < KT; ++d) {
            float4 a = *(const float4*)&As[d][myq];
            float4 b = *(const float4*)&Bs[d][myp];
            float av[4] = {a.x, a.y, a.z, a.w};
            float bv[4] = {b.x, b.y, b.z, b.w};
            #pragma unroll
            for (int i = 0; i < 4; ++i)
                #pragma unroll
                for (int j = 0; j < 4; ++j)
                    acc[i][j] = fmaf(av[i], bv[j], acc[i][j]);
        }
    }

    float qnr[4], knr[4];
    #pragma unroll
    for (int i = 0; i < 4; ++i) qnr[i] = qn[qbase + myq + i];
    #pragma unroll
    for (int j = 0; j < 4; ++j) knr[j] = kn[pbase + myp + j];
    #pragma unroll
    for (int i = 0; i < 4; ++i) {
        float4 r;
        float* rp = (float*)&r;
        #pragma unroll
        for (int j = 0; j < 4; ++j) {
            float denom = fmaxf(qnr[i] * knr[j], EPS);
            rp[j] = 1.0f - acc[i][j] / denom;
        }
        int row = qbase + myq + i;
        float* dst = matchbase + (size_t)(row >> 2) * SPAN + (size_t)(row & 3) * POOL
                     + pbase + myp;
        *(float4*)dst = r;
    }
}

// ---------------------------------------------------------------------------
// Kernel 3 (fused topk + gather): block b handles rows 4b..4b+3.
// Phase 1: each wave top-5's its own match row (read from own span).
// Barrier. Phase 2: each wave gather-copies its 5 prompts into its own
// fifth of the span.
__device__ __forceinline__ bool before_(float va, int ia, float vb, int ib) {
    return (va < vb) || (va == vb && ia < ib);
}

__device__ __forceinline__ void insert5(float v[SEL], int id[SEL], float nv, int ni) {
    if (!before_(nv, ni, v[SEL - 1], id[SEL - 1])) return;
    v[SEL - 1] = nv; id[SEL - 1] = ni;
    #pragma unroll
    for (int j = SEL - 1; j > 0; --j) {
        if (before_(v[j], id[j], v[j - 1], id[j - 1])) {
            float tv = v[j]; v[j] = v[j - 1]; v[j - 1] = tv;
            int ti = id[j]; id[j] = id[j - 1]; id[j - 1] = ti;
        }
    }
}

__global__ __launch_bounds__(256) void topk_gather_kernel(
    const float* mbase,                     // = sel (aliases selo; no restrict)
    const float* __restrict__ prompts,
    float* __restrict__ sim,
    float* selo) {
    const int b = blockIdx.x;               // 0..1023
    const int w = threadIdx.x >> 6;         // wave 0..3
    const int lane = threadIdx.x & 63;
    const int row = b * 4 + w;

    const float* m = mbase + (size_t)b * SPAN + (size_t)w * POOL;

    float v[SEL]; int id[SEL];
    #pragma unroll
    for (int j = 0; j < SEL; ++j) { v[j] = 3.402823466e+38f; id[j] = 0x7fffffff; }

    #pragma unroll
    for (int t = 0; t < POOL / 64; ++t) {
        int i = lane + (t << 6);
        insert5(v, id, m[i], i);
    }

    #pragma unroll
    for (int k = 1; k <= 32; k <<= 1) {
        float pv[SEL]; int pi[SEL];
        #pragma unroll
        for (int j = 0; j < SEL; ++j) {
            pv[j] = __shfl_xor(v[j], k);
            pi[j] = __shfl_xor(id[j], k);
        }
        #pragma unroll
        for (int j = 0; j < SEL; ++j) insert5(v, id, pv[j], pi[j]);
    }
    // all 64 lanes now hold the identical sorted top-5

    if (lane == 0) {
        #pragma unroll
        for (int j = 0; j < SEL; ++j) sim[row * SEL + j] = v[j];
    }

    __syncthreads();   // all match reads in this block complete before writes

    float* span = selo + (size_t)b * SPAN;
    #pragma unroll
    for (int j = 0; j < SEL; ++j) {
        const float4* src = (const float4*)(prompts + (size_t)id[j] * PF);
        float4* dst = (float4*)(span + (size_t)(w * SEL + j) * PF);
        #pragma unroll
        for (int i = lane; i < PF / 4; i += 64) dst[i] = src[i];
    }
}

// ---------------------------------------------------------------------------
extern "C" void kernel_launch(void* const* d_in, const int* in_sizes, int n_in,
                              void* d_out, int out_size, void* d_ws, size_t ws_size,
                              hipStream_t stream) {
    const float* query   = (const float*)d_in[0];   // [4096, 768]
    const float* pkey    = (const float*)d_in[1];   // [1024, 768]
    const float* prompts = (const float*)d_in[2];   // [1024, 5, 768]

    float* out = (float*)d_out;
    float* sim = out;                       // [4096, 5]
    float* sel = out + (size_t)B_ * SEL;    // [4096, 5, 5, 768] + scratch layout

    float* qn = sel + 4096;                 // span 0, after match rows 0..3
    float* kn = sel + 8192;

    norms_kernel<<<dim3((B_ + POOL) / 4), 256, 0, stream>>>(query, pkey, qn, kn);
    match_gemm<<<dim3(POOL / BP, B_ / BQ), 256, 0, stream>>>(query, pkey, qn, kn, sel);
    topk_gather_kernel<<<dim3(B_ / 4), 256, 0, stream>>>(sel, prompts, sim, sel);
}